// Round 6
// baseline (340.869 us; speedup 1.0000x reference)
//
#include <hip/hip_runtime.h>
#include <cstdint>
#include <cstddef>

#define NROWS 262144
#define EMB 256
#define NB 512
#define NCOPY 8
#define SLOPE 0.01f

typedef __attribute__((ext_vector_type(8))) short short8;
typedef __attribute__((ext_vector_type(4))) float f32x4;

__device__ __forceinline__ unsigned short f2bf(float f) {
    unsigned u = __float_as_uint(f);
    u += 0x7FFFu + ((u >> 16) & 1u);
    return (unsigned short)(u >> 16);
}

__device__ __forceinline__ short8 pack8(const float4& lo, const float4& hi) {
    short8 s;
    s[0] = (short)f2bf(lo.x); s[1] = (short)f2bf(lo.y);
    s[2] = (short)f2bf(lo.z); s[3] = (short)f2bf(lo.w);
    s[4] = (short)f2bf(hi.x); s[5] = (short)f2bf(hi.y);
    s[6] = (short)f2bf(hi.z); s[7] = (short)f2bf(hi.w);
    return s;
}

// ---------- init: zero xgPart (8 copies) + dPart ----------
__global__ __launch_bounds__(256) void k_init(float4* xgPart4, float4* dPart4) {
    int i = blockIdx.x * 256 + threadIdx.x;
    if (i < NCOPY * NB * EMB / 4) xgPart4[i] = (float4){0.f, 0.f, 0.f, 0.f};
    else dPart4[i - NCOPY * NB * EMB / 4] = (float4){0.f, 0.f, 0.f, 0.f};
}

// ---------- prep: transpose W_feat -> bf16 Wt[col][k] ----------
__global__ __launch_bounds__(256) void k_prep(const float* __restrict__ Wf,
                                              unsigned short* __restrict__ Wt) {
    int b = blockIdx.x, t = threadIdx.x;
    float v = Wf[(size_t)b * EMB + t];   // W_feat[k=b][col=t]
    Wt[(size_t)t * EMB + b] = f2bf(v);   // Wt[col][k]
}

// ---------- fused: gate + exp + bf16 MFMA feat GEMM + weighted segment reduce ----------
// 1024 threads = 16 waves (wr 0..7 x wc 0..1). Tile 256 rows x 256 cols, grid 1024.
// Full Wt (128KB bf16) staged once into LDS (chunk-XOR swizzled); A operand loaded
// 32-deep into registers per wave; main MFMA loop is pure reg+LDS, ZERO barriers.
__global__ __launch_bounds__(1024) void k_fused(const float* __restrict__ x,
                                                const unsigned short* __restrict__ Wt,
                                                const float* __restrict__ wm,
                                                const float* __restrict__ bfeat,
                                                const int* __restrict__ bind,
                                                float* __restrict__ dPart,
                                                float* __restrict__ xgPart) {
    __shared__ unsigned short wt_s[256][256];   // 128 KB, chunk-swizzled
    __shared__ float wm_s[256];
    __shared__ float w_s[256];
    __shared__ float pxg[2][256];
    __shared__ float pden[2];
    __shared__ int   seg_s[256];
    __shared__ int   segid_s[16];
    __shared__ int   uni_s[16];

    const int t    = threadIdx.x;
    const int lane = t & 63;
    const int w    = t >> 6;
    const int wr   = w >> 1, wc = w & 1;
    const int fr   = lane & 15;
    const int fg   = lane >> 4;
    const size_t r0 = (size_t)blockIdx.x * 256;
    const int cp   = blockIdx.x & (NCOPY - 1);

    // ---- stage Wt -> LDS, 16B chunk c of col stored at slot c^(col&15) ----
    {
        const int col = t >> 2;
        const int q   = t & 3;
        const unsigned short* wg = Wt + (size_t)col * EMB + q * 64;
#pragma unroll
        for (int i = 0; i < 8; i++) {
            const int c = q * 8 + i;
            *reinterpret_cast<short8*>(&wt_s[col][(c ^ (col & 15)) << 3]) =
                *reinterpret_cast<const short8*>(wg + i * 8);
        }
    }
    if (t < 256) {
        wm_s[t] = wm[t];
        seg_s[t] = bind[r0 + t];
        pxg[0][t] = 0.f;
        pxg[1][t] = 0.f;
    }
    if (t < 2) pden[t] = 0.f;
    __syncthreads();   // wt_s / wm_s / seg_s / pxg ready

    const int sid0 = seg_s[0];
    const int sid1 = seg_s[255];
    if (t < 16) {
        int s0 = seg_s[t * 16], ok = 1;
#pragma unroll
        for (int i = 1; i < 16; i++) ok &= (seg_s[t * 16 + i] == s0);
        segid_s[t] = s0;
        uni_s[t]   = ok;
    }

    // ---- A: load this wave's entire 32-row x 256-col slice into registers ----
    const float* xr0 = x + (r0 + wr * 32 + fr) * EMB + fg * 8;
    const float* xr1 = xr0 + 16 * EMB;
    float4 ax0[16], ax1[16];
#pragma unroll
    for (int i = 0; i < 8; i++) {
        ax0[2 * i]     = *reinterpret_cast<const float4*>(xr0 + i * 32);
        ax0[2 * i + 1] = *reinterpret_cast<const float4*>(xr0 + i * 32 + 4);
        ax1[2 * i]     = *reinterpret_cast<const float4*>(xr1 + i * 32);
        ax1[2 * i + 1] = *reinterpret_cast<const float4*>(xr1 + i * 32 + 4);
    }

    // ---- gate partials + convert A to bf16 fragments ----
    float gp0 = 0.f, gp1 = 0.f;
    short8 ab0[8], ab1[8];
#pragma unroll
    for (int ks = 0; ks < 8; ks++) {
        const float4 wa = *reinterpret_cast<const float4*>(&wm_s[ks * 32 + fg * 8]);
        const float4 wb = *reinterpret_cast<const float4*>(&wm_s[ks * 32 + fg * 8 + 4]);
        gp0 += ax0[2 * ks].x * wa.x + ax0[2 * ks].y * wa.y + ax0[2 * ks].z * wa.z + ax0[2 * ks].w * wa.w
             + ax0[2 * ks + 1].x * wb.x + ax0[2 * ks + 1].y * wb.y + ax0[2 * ks + 1].z * wb.z + ax0[2 * ks + 1].w * wb.w;
        gp1 += ax1[2 * ks].x * wa.x + ax1[2 * ks].y * wa.y + ax1[2 * ks].z * wa.z + ax1[2 * ks].w * wa.w
             + ax1[2 * ks + 1].x * wb.x + ax1[2 * ks + 1].y * wb.y + ax1[2 * ks + 1].z * wb.z + ax1[2 * ks + 1].w * wb.w;
        ab0[ks] = pack8(ax0[2 * ks], ax0[2 * ks + 1]);
        ab1[ks] = pack8(ax1[2 * ks], ax1[2 * ks + 1]);
    }
    gp0 += __shfl_xor(gp0, 16, 64); gp0 += __shfl_xor(gp0, 32, 64);
    gp1 += __shfl_xor(gp1, 16, 64); gp1 += __shfl_xor(gp1, 32, 64);
    // exp(b_mask) cancels in the softmax -> dropped
    if (wc == 0 && lane < 16) {
        w_s[wr * 32 + lane]      = expf(gp0);
        w_s[wr * 32 + 16 + lane] = expf(gp1);
    }

    // ---- MFMA loop: pure registers + LDS, no barriers ----
    f32x4 acc[2][8];
#pragma unroll
    for (int m = 0; m < 2; m++)
#pragma unroll
        for (int n = 0; n < 8; n++) acc[m][n] = (f32x4){0.f, 0.f, 0.f, 0.f};

#pragma unroll
    for (int ks = 0; ks < 8; ks++) {
        const int cs = (((ks * 4 + fg) ^ fr)) << 3;   // swizzled 16B chunk slot
#pragma unroll
        for (int n = 0; n < 8; n++) {
            const short8 b = *reinterpret_cast<const short8*>(&wt_s[wc * 128 + n * 16 + fr][cs]);
            acc[0][n] = __builtin_amdgcn_mfma_f32_16x16x32_bf16(ab0[ks], b, acc[0][n], 0, 0, 0);
            acc[1][n] = __builtin_amdgcn_mfma_f32_16x16x32_bf16(ab1[ks], b, acc[1][n], 0, 0, 0);
        }
    }
    __syncthreads();   // w_s, segid_s/uni_s ready; all waves done with wt_s

    // ---- denom partials ----
    if (t < 16) {
        if (uni_s[t]) {
            float s = 0.f;
#pragma unroll
            for (int i = 0; i < 16; i++) s += w_s[t * 16 + i];
            const int sid = segid_s[t];
            if (sid == sid0)      atomicAdd(&pden[0], s);
            else if (sid == sid1) atomicAdd(&pden[1], s);
            else atomicAdd(&dPart[cp * NB + sid], s);
        } else {
            for (int i = 0; i < 16; i++) {
                const int sd = seg_s[t * 16 + i];
                const float e = w_s[t * 16 + i];
                if (sd == sid0)      atomicAdd(&pden[0], e);
                else if (sd == sid1) atomicAdd(&pden[1], e);
                else atomicAdd(&dPart[cp * NB + sd], e);
            }
        }
    }

    // ---- epilogue: bias -> leaky -> *e -> segmented reduce -> LDS slots ----
#pragma unroll
    for (int m = 0; m < 2; m++) {
        const int g    = wr * 2 + m;
        const int uni  = uni_s[g];
        const int sid  = segid_s[g];
        const int rowb = wr * 32 + m * 16;
#pragma unroll
        for (int n = 0; n < 8; n++) {
            const int col = wc * 128 + n * 16 + fr;
            const float bia = bfeat[col];
            float vr[4];
#pragma unroll
            for (int r = 0; r < 4; r++) {
                const int row = rowb + fg * 4 + r;
                float v = acc[m][n][r] + bia;
                v = (v >= 0.f) ? v : SLOPE * v;
                vr[r] = v * w_s[row];
            }
            if (uni) {
                float s = vr[0] + vr[1] + vr[2] + vr[3];
                s += __shfl_xor(s, 16, 64);
                s += __shfl_xor(s, 32, 64);
                if (fg == 0) {
                    if (sid == sid0)      atomicAdd(&pxg[0][col], s);
                    else if (sid == sid1) atomicAdd(&pxg[1][col], s);
                    else atomicAdd(&xgPart[((size_t)(cp * NB + sid) << 8) + col], s);
                }
            } else {
#pragma unroll
                for (int r = 0; r < 4; r++) {
                    const int sd = seg_s[rowb + fg * 4 + r];
                    if (sd == sid0)      atomicAdd(&pxg[0][col], vr[r]);
                    else if (sd == sid1) atomicAdd(&pxg[1][col], vr[r]);
                    else atomicAdd(&xgPart[((size_t)(cp * NB + sd) << 8) + col], vr[r]);
                }
            }
        }
    }
    __syncthreads();

    // ---- flush block partials into XCD-striped copies ----
    if (t < 256) {
        atomicAdd(&xgPart[((size_t)(cp * NB + sid0) << 8) + t], pxg[0][t]);
    } else if (t < 512) {
        if (sid1 != sid0)
            atomicAdd(&xgPart[((size_t)(cp * NB + sid1) << 8) + (t - 256)], pxg[1][t - 256]);
    } else if (t == 512) {
        atomicAdd(&dPart[cp * NB + sid0], pden[0]);
    } else if (t == 513) {
        if (sid1 != sid0) atomicAdd(&dPart[cp * NB + sid1], pden[1]);
    }
}

// ---------- out = leaky_relu([xg/denom, xg_prev] @ W_t + b_t) + xg_prev ----------
__global__ __launch_bounds__(256) void k_out(const float* __restrict__ xgPart,
                                             const float* __restrict__ dPart,
                                             const float* __restrict__ xgp,
                                             const float* __restrict__ Wtr,
                                             const float* __restrict__ bt,
                                             float* __restrict__ out) {
    __shared__ float h[8][512];
    const int c  = threadIdx.x;
    const int b0 = blockIdx.x * 8;
#pragma unroll
    for (int r = 0; r < 8; r++) {
        const int b = b0 + r;
        float den = 0.f, s = 0.f;
#pragma unroll
        for (int cpy = 0; cpy < NCOPY; cpy++) {
            den += dPart[cpy * NB + b];
            s   += xgPart[((size_t)(cpy * NB + b) << 8) + c];
        }
        h[r][c]       = s / fmaxf(den, 1e-16f);
        h[r][EMB + c] = xgp[(size_t)b * EMB + c];
    }
    __syncthreads();
    float acc[8] = {0.f, 0.f, 0.f, 0.f, 0.f, 0.f, 0.f, 0.f};
    for (int k = 0; k < 2 * EMB; k++) {
        float wv = Wtr[(size_t)k * EMB + c];
#pragma unroll
        for (int r = 0; r < 8; r++) acc[r] += h[r][k] * wv;
    }
#pragma unroll
    for (int r = 0; r < 8; r++) {
        float v = acc[r] + bt[c];
        v = (v >= 0.f) ? v : SLOPE * v;
        out[(size_t)(b0 + r) * EMB + c] = v + xgp[(size_t)(b0 + r) * EMB + c];
    }
}

extern "C" void kernel_launch(void* const* d_in, const int* in_sizes, int n_in,
                              void* d_out, int out_size, void* d_ws, size_t ws_size,
                              hipStream_t stream) {
    const float* xgp  = (const float*)d_in[0];
    const float* x    = (const float*)d_in[1];
    const int*   bind = (const int*)d_in[2];
    const float* Wm   = (const float*)d_in[3];
    const float* Wf   = (const float*)d_in[5];
    const float* bf   = (const float*)d_in[6];
    const float* Wtr  = (const float*)d_in[7];
    const float* bt   = (const float*)d_in[8];
    float* out = (float*)d_out;

    char* ws = (char*)d_ws;
    unsigned short* Wt     = (unsigned short*)ws;                 // 128 KB
    float*          dPart  = (float*)(ws + 131072);               // 8*512 f32 = 16 KB
    float*          xgPart = (float*)(ws + 131072 + 16384);       // 8*512*256 f32 = 4 MB

    hipLaunchKernelGGL(k_init,  dim3(1028),        dim3(256),  0, stream,
                       (float4*)xgPart, (float4*)dPart);
    hipLaunchKernelGGL(k_prep,  dim3(256),         dim3(256),  0, stream, Wf, Wt);
    hipLaunchKernelGGL(k_fused, dim3(NROWS / 256), dim3(1024), 0, stream,
                       x, Wt, Wm, bf, bind, dPart, xgPart);
    hipLaunchKernelGGL(k_out,   dim3(NB / 8),      dim3(256),  0, stream,
                       xgPart, dPart, xgp, Wtr, bt, out);
}

// Round 7
// 214.551 us; speedup vs baseline: 1.5888x; 1.5888x over previous
//
#include <hip/hip_runtime.h>
#include <cstdint>
#include <cstddef>

#define NROWS 262144
#define EMB 256
#define NB 512
#define NCOPY 8
#define SLOPE 0.01f

typedef __attribute__((ext_vector_type(8))) short short8;
typedef __attribute__((ext_vector_type(4))) float f32x4;

__device__ __forceinline__ unsigned short f2bf(float f) {
    unsigned u = __float_as_uint(f);
    u += 0x7FFFu + ((u >> 16) & 1u);
    return (unsigned short)(u >> 16);
}

__device__ __forceinline__ short8 pack8(const float4& lo, const float4& hi) {
    short8 s;
    s[0] = (short)f2bf(lo.x); s[1] = (short)f2bf(lo.y);
    s[2] = (short)f2bf(lo.z); s[3] = (short)f2bf(lo.w);
    s[4] = (short)f2bf(hi.x); s[5] = (short)f2bf(hi.y);
    s[6] = (short)f2bf(hi.z); s[7] = (short)f2bf(hi.w);
    return s;
}

// async 16B global -> LDS (DMA, no VGPR round trip)
__device__ __forceinline__ void gld16f(float* l, const float* g) {
    __builtin_amdgcn_global_load_lds(
        (const __attribute__((address_space(1))) unsigned int*)g,
        (__attribute__((address_space(3))) unsigned int*)l, 16, 0, 0);
}
__device__ __forceinline__ void gld16u(unsigned short* l, const unsigned short* g) {
    __builtin_amdgcn_global_load_lds(
        (const __attribute__((address_space(1))) unsigned int*)g,
        (__attribute__((address_space(3))) unsigned int*)l, 16, 0, 0);
}

// ---------- init: zero xgPart (8 copies) + dPart ----------
__global__ __launch_bounds__(256) void k_init(float4* xgPart4, float4* dPart4) {
    int i = blockIdx.x * 256 + threadIdx.x;
    if (i < NCOPY * NB * EMB / 4) xgPart4[i] = (float4){0.f, 0.f, 0.f, 0.f};
    else dPart4[i - NCOPY * NB * EMB / 4] = (float4){0.f, 0.f, 0.f, 0.f};
}

// ---------- prep: transpose W_feat -> bf16 Wt[col][k] ----------
__global__ __launch_bounds__(256) void k_prep(const float* __restrict__ Wf,
                                              unsigned short* __restrict__ Wt) {
    int b = blockIdx.x, t = threadIdx.x;
    float v = Wf[(size_t)b * EMB + t];   // W_feat[k=b][col=t]
    Wt[(size_t)t * EMB + b] = f2bf(v);   // Wt[col][k]
}

// ---------- fused: gate + exp + bf16 MFMA feat GEMM + weighted segment reduce ----------
// 256 threads (4 waves, wr x wc = 2x2). Tile 64 rows x 256 cols, BK=32, 8 K-steps.
// BOTH operands double-buffered in LDS via global_load_lds DMA; compute phase is
// pure LDS+VALU+MFMA (zero global loads -> nothing to spill/serialize).
__global__ __launch_bounds__(256, 2) void k_fused(const float* __restrict__ x,
                                                  const unsigned short* __restrict__ Wt,
                                                  const float* __restrict__ wm,
                                                  const float* __restrict__ bfeat,
                                                  const int* __restrict__ bind,
                                                  float* __restrict__ dPart,
                                                  float* __restrict__ xgPart) {
    __shared__ float          xbuf[2][64 * 32];    // A: 2 x 8 KB (row-chunk XOR swizzled)
    __shared__ unsigned short bbuf[2][32 * 256];   // B: 2 x 16 KB, [k-chunk q][col] slabs
    __shared__ float wm_s[256];
    __shared__ float w_s[64];
    __shared__ float pxg[2][256];
    __shared__ float pden[2];
    __shared__ int   seg_s[64];
    __shared__ int   segid_s[4];
    __shared__ int   uni_s[4];

    const int t    = threadIdx.x;
    const int lane = t & 63;
    const int w    = t >> 6;
    const int wr   = w >> 1, wc = w & 1;
    const int fr   = lane & 15;
    const int fg   = lane >> 4;
    const size_t r0 = (size_t)blockIdx.x * 64;
    const int cp   = blockIdx.x & (NCOPY - 1);

    wm_s[t] = wm[t];
    pxg[0][t] = 0.f;
    pxg[1][t] = 0.f;
    if (t < 2) pden[t] = 0.f;
    if (t < 64) seg_s[t] = bind[r0 + t];

    // ---- prologue: stage step 0 into buf0 ----
    // A: 64 rows x 32 k f32 = 512 chunks; chunk c of row stored at slot c^(row&7)
    // (pre-swizzled global source, linear LDS dest -- guide rule m173)
#pragma unroll
    for (int q = 0; q < 2; q++) {
        const int i = q * 256 + t;
        const int row = i >> 3, c = i & 7;
        const int cs = c ^ (row & 7);
        gld16f(&xbuf[0][i * 4], x + ((r0 + row) << 8) + (cs << 2));
    }
    // B: slab q holds k-chunk q (8 k) of all 256 cols; dest q*4096 + t*16 bytes
#pragma unroll
    for (int q = 0; q < 4; q++) {
        gld16u(&bbuf[0][q * 2048 + t * 8], Wt + ((size_t)t << 8) + q * 8);
    }
    __syncthreads();   // smem init visible + buf0 DMA drained

    const int sid0 = seg_s[0];
    const int sid1 = seg_s[63];
    if (t < 4) {
        int s0 = seg_s[t * 16], ok = 1;
#pragma unroll
        for (int i = 1; i < 16; i++) ok &= (seg_s[t * 16 + i] == s0);
        segid_s[t] = s0;
        uni_s[t]   = ok;
    }

    f32x4 acc[2][8];
#pragma unroll
    for (int m = 0; m < 2; m++)
#pragma unroll
        for (int n = 0; n < 8; n++) acc[m][n] = (f32x4){0.f, 0.f, 0.f, 0.f};
    float gp0 = 0.f, gp1 = 0.f;

    // ---- main loop: 8 K-steps of BK=32 ----
#pragma unroll
    for (int s = 0; s < 8; s++) {
        const int cur = s & 1;
        if (s < 7) {   // stage step s+1 into other buffer (issue-early, drain at barrier)
            const int kt = (s + 1) * 32;
#pragma unroll
            for (int q = 0; q < 2; q++) {
                const int i = q * 256 + t;
                const int row = i >> 3, c = i & 7;
                const int cs = c ^ (row & 7);
                gld16f(&xbuf[cur ^ 1][i * 4], x + ((r0 + row) << 8) + kt + (cs << 2));
            }
#pragma unroll
            for (int q = 0; q < 4; q++) {
                gld16u(&bbuf[cur ^ 1][q * 2048 + t * 8], Wt + ((size_t)t << 8) + kt + q * 8);
            }
        }

        // compute step s: pure LDS
        const float* xb = &xbuf[cur][0];
        const unsigned short* bb = &bbuf[cur][0];
        short8 b[8];
#pragma unroll
        for (int n = 0; n < 8; n++)
            b[n] = *reinterpret_cast<const short8*>(&bb[fg * 2048 + ((wc * 128 + n * 16 + fr) << 3)]);

        const float4 wa = *reinterpret_cast<const float4*>(&wm_s[s * 32 + fg * 8]);
        const float4 wb = *reinterpret_cast<const float4*>(&wm_s[s * 32 + fg * 8 + 4]);
        {
            const int r  = wr * 32 + fr;
            const int sl = (fg * 2) ^ (r & 7);
            const float4 lo = *reinterpret_cast<const float4*>(&xb[r * 32 + sl * 4]);
            const float4 hi = *reinterpret_cast<const float4*>(&xb[r * 32 + (sl ^ 1) * 4]);
            gp0 += lo.x * wa.x + lo.y * wa.y + lo.z * wa.z + lo.w * wa.w
                 + hi.x * wb.x + hi.y * wb.y + hi.z * wb.z + hi.w * wb.w;
            const short8 a = pack8(lo, hi);
#pragma unroll
            for (int n = 0; n < 8; n++)
                acc[0][n] = __builtin_amdgcn_mfma_f32_16x16x32_bf16(a, b[n], acc[0][n], 0, 0, 0);
        }
        {
            const int r  = wr * 32 + 16 + fr;
            const int sl = (fg * 2) ^ (r & 7);
            const float4 lo = *reinterpret_cast<const float4*>(&xb[r * 32 + sl * 4]);
            const float4 hi = *reinterpret_cast<const float4*>(&xb[r * 32 + (sl ^ 1) * 4]);
            gp1 += lo.x * wa.x + lo.y * wa.y + lo.z * wa.z + lo.w * wa.w
                 + hi.x * wb.x + hi.y * wb.y + hi.z * wb.z + hi.w * wb.w;
            const short8 a = pack8(lo, hi);
#pragma unroll
            for (int n = 0; n < 8; n++)
                acc[1][n] = __builtin_amdgcn_mfma_f32_16x16x32_bf16(a, b[n], acc[1][n], 0, 0, 0);
        }
        __syncthreads();   // next-step DMA drained + buf[cur] released
    }

    // ---- gate -> e ----
    gp0 += __shfl_xor(gp0, 16, 64); gp0 += __shfl_xor(gp0, 32, 64);
    gp1 += __shfl_xor(gp1, 16, 64); gp1 += __shfl_xor(gp1, 32, 64);
    // exp(b_mask) cancels in the softmax -> dropped
    if (wc == 0 && lane < 16) {
        w_s[wr * 32 + lane]      = expf(gp0);
        w_s[wr * 32 + 16 + lane] = expf(gp1);
    }
    __syncthreads();

    // ---- denom partials (LDS slots, global fallback for >2-segment blocks) ----
    if (t < 4) {
        if (uni_s[t]) {
            float s = 0.f;
#pragma unroll
            for (int i = 0; i < 16; i++) s += w_s[t * 16 + i];
            const int sid = segid_s[t];
            if (sid == sid0)      atomicAdd(&pden[0], s);
            else if (sid == sid1) atomicAdd(&pden[1], s);
            else atomicAdd(&dPart[cp * NB + sid], s);
        } else {
            for (int i = 0; i < 16; i++) {
                const int sd = seg_s[t * 16 + i];
                const float e = w_s[t * 16 + i];
                if (sd == sid0)      atomicAdd(&pden[0], e);
                else if (sd == sid1) atomicAdd(&pden[1], e);
                else atomicAdd(&dPart[cp * NB + sd], e);
            }
        }
    }

    // ---- epilogue: bias -> leaky -> *e -> segmented reduce -> LDS slots ----
#pragma unroll
    for (int m = 0; m < 2; m++) {
        const int g    = wr * 2 + m;
        const int uni  = uni_s[g];
        const int sid  = segid_s[g];
        const int rowb = wr * 32 + m * 16;
#pragma unroll
        for (int n = 0; n < 8; n++) {
            const int col = wc * 128 + n * 16 + fr;
            const float bia = bfeat[col];
            float vr[4];
#pragma unroll
            for (int r = 0; r < 4; r++) {
                const int row = rowb + fg * 4 + r;
                float v = acc[m][n][r] + bia;
                v = (v >= 0.f) ? v : SLOPE * v;
                vr[r] = v * w_s[row];
            }
            if (uni) {
                float s = vr[0] + vr[1] + vr[2] + vr[3];
                s += __shfl_xor(s, 16, 64);
                s += __shfl_xor(s, 32, 64);
                if (fg == 0) {
                    if (sid == sid0)      atomicAdd(&pxg[0][col], s);
                    else if (sid == sid1) atomicAdd(&pxg[1][col], s);
                    else atomicAdd(&xgPart[((size_t)(cp * NB + sid) << 8) + col], s);
                }
            } else {
#pragma unroll
                for (int r = 0; r < 4; r++) {
                    const int sd = seg_s[rowb + fg * 4 + r];
                    if (sd == sid0)      atomicAdd(&pxg[0][col], vr[r]);
                    else if (sd == sid1) atomicAdd(&pxg[1][col], vr[r]);
                    else atomicAdd(&xgPart[((size_t)(cp * NB + sd) << 8) + col], vr[r]);
                }
            }
        }
    }
    __syncthreads();

    // ---- flush block partials into XCD-striped copies ----
    atomicAdd(&xgPart[((size_t)(cp * NB + sid0) << 8) + t], pxg[0][t]);
    if (sid1 != sid0)
        atomicAdd(&xgPart[((size_t)(cp * NB + sid1) << 8) + t], pxg[1][t]);
    if (t == 0) atomicAdd(&dPart[cp * NB + sid0], pden[0]);
    if (t == 1 && sid1 != sid0) atomicAdd(&dPart[cp * NB + sid1], pden[1]);
}

// ---------- out = leaky_relu([xg/denom, xg_prev] @ W_t + b_t) + xg_prev ----------
__global__ __launch_bounds__(256) void k_out(const float* __restrict__ xgPart,
                                             const float* __restrict__ dPart,
                                             const float* __restrict__ xgp,
                                             const float* __restrict__ Wtr,
                                             const float* __restrict__ bt,
                                             float* __restrict__ out) {
    __shared__ float h[8][512];
    const int c  = threadIdx.x;
    const int b0 = blockIdx.x * 8;
#pragma unroll
    for (int r = 0; r < 8; r++) {
        const int b = b0 + r;
        float den = 0.f, s = 0.f;
#pragma unroll
        for (int cpy = 0; cpy < NCOPY; cpy++) {
            den += dPart[cpy * NB + b];
            s   += xgPart[((size_t)(cpy * NB + b) << 8) + c];
        }
        h[r][c]       = s / fmaxf(den, 1e-16f);
        h[r][EMB + c] = xgp[(size_t)b * EMB + c];
    }
    __syncthreads();
    float acc[8] = {0.f, 0.f, 0.f, 0.f, 0.f, 0.f, 0.f, 0.f};
    for (int k = 0; k < 2 * EMB; k++) {
        float wv = Wtr[(size_t)k * EMB + c];
#pragma unroll
        for (int r = 0; r < 8; r++) acc[r] += h[r][k] * wv;
    }
#pragma unroll
    for (int r = 0; r < 8; r++) {
        float v = acc[r] + bt[c];
        v = (v >= 0.f) ? v : SLOPE * v;
        out[(size_t)(b0 + r) * EMB + c] = v + xgp[(size_t)(b0 + r) * EMB + c];
    }
}

extern "C" void kernel_launch(void* const* d_in, const int* in_sizes, int n_in,
                              void* d_out, int out_size, void* d_ws, size_t ws_size,
                              hipStream_t stream) {
    const float* xgp  = (const float*)d_in[0];
    const float* x    = (const float*)d_in[1];
    const int*   bind = (const int*)d_in[2];
    const float* Wm   = (const float*)d_in[3];
    const float* Wf   = (const float*)d_in[5];
    const float* bf   = (const float*)d_in[6];
    const float* Wtr  = (const float*)d_in[7];
    const float* bt   = (const float*)d_in[8];
    float* out = (float*)d_out;

    char* ws = (char*)d_ws;
    unsigned short* Wt     = (unsigned short*)ws;                 // 128 KB
    float*          dPart  = (float*)(ws + 131072);               // 8*512 f32 = 16 KB
    float*          xgPart = (float*)(ws + 131072 + 16384);       // 8*512*256 f32 = 4 MB

    hipLaunchKernelGGL(k_init,  dim3(1028),       dim3(256), 0, stream,
                       (float4*)xgPart, (float4*)dPart);
    hipLaunchKernelGGL(k_prep,  dim3(256),        dim3(256), 0, stream, Wf, Wt);
    hipLaunchKernelGGL(k_fused, dim3(NROWS / 64), dim3(256), 0, stream,
                       x, Wt, Wm, bf, bind, dPart, xgPart);
    hipLaunchKernelGGL(k_out,   dim3(NB / 8),     dim3(256), 0, stream,
                       xgPart, dPart, xgp, Wtr, bt, out);
}

// Round 8
// 213.731 us; speedup vs baseline: 1.5949x; 1.0038x over previous
//
#include <hip/hip_runtime.h>
#include <cstdint>
#include <cstddef>

#define NROWS 262144
#define EMB 256
#define NB 512
#define NCOPY 8
#define SLOPE 0.01f

typedef __attribute__((ext_vector_type(8))) short short8;
typedef __attribute__((ext_vector_type(4))) float f32x4;

__device__ __forceinline__ unsigned short f2bf(float f) {
    unsigned u = __float_as_uint(f);
    u += 0x7FFFu + ((u >> 16) & 1u);
    return (unsigned short)(u >> 16);
}

__device__ __forceinline__ short8 pack8(const float4& lo, const float4& hi) {
    short8 s;
    s[0] = (short)f2bf(lo.x); s[1] = (short)f2bf(lo.y);
    s[2] = (short)f2bf(lo.z); s[3] = (short)f2bf(lo.w);
    s[4] = (short)f2bf(hi.x); s[5] = (short)f2bf(hi.y);
    s[6] = (short)f2bf(hi.z); s[7] = (short)f2bf(hi.w);
    return s;
}

// async 16B global -> LDS (DMA, no VGPR round trip)
__device__ __forceinline__ void gld16f(float* l, const float* g) {
    __builtin_amdgcn_global_load_lds(
        (const __attribute__((address_space(1))) unsigned int*)g,
        (__attribute__((address_space(3))) unsigned int*)l, 16, 0, 0);
}
__device__ __forceinline__ void gld16u(unsigned short* l, const unsigned short* g) {
    __builtin_amdgcn_global_load_lds(
        (const __attribute__((address_space(1))) unsigned int*)g,
        (__attribute__((address_space(3))) unsigned int*)l, 16, 0, 0);
}

// ---------- init: zero xgPart (8 copies) + dPart ----------
__global__ __launch_bounds__(256) void k_init(float4* xgPart4, float4* dPart4) {
    int i = blockIdx.x * 256 + threadIdx.x;
    if (i < NCOPY * NB * EMB / 4) xgPart4[i] = (float4){0.f, 0.f, 0.f, 0.f};
    else dPart4[i - NCOPY * NB * EMB / 4] = (float4){0.f, 0.f, 0.f, 0.f};
}

// ---------- prep: transpose W_feat -> bf16 Wt[col][k] ----------
__global__ __launch_bounds__(256) void k_prep(const float* __restrict__ Wf,
                                              unsigned short* __restrict__ Wt) {
    int b = blockIdx.x, t = threadIdx.x;
    float v = Wf[(size_t)b * EMB + t];   // W_feat[k=b][col=t]
    Wt[(size_t)t * EMB + b] = f2bf(v);   // Wt[col][k]
}

// stage K-step (32 k) into buffer B: A 64x32 f32 (row-chunk XOR swizzled src),
// B slab-of-4 [k-chunk][col] bf16. 6 DMA instructions per thread.
#define STAGE(B, KT) do {                                                       \
    _Pragma("unroll")                                                           \
    for (int q = 0; q < 2; q++) {                                               \
        const int i_ = q * 256 + t;                                             \
        const int row_ = i_ >> 3, c_ = i_ & 7;                                  \
        const int cs_ = c_ ^ (row_ & 7);                                        \
        gld16f(&xbuf[B][i_ * 4], x + ((r0 + row_) << 8) + (KT) + (cs_ << 2));   \
    }                                                                           \
    _Pragma("unroll")                                                           \
    for (int q = 0; q < 4; q++) {                                               \
        gld16u(&bbuf[B][q * 2048 + t * 8], Wt + ((size_t)t << 8) + (KT) + q * 8); \
    }                                                                           \
} while (0)

// ---------- fused: gate + exp + bf16 MFMA feat GEMM + weighted segment reduce ----------
// 256 threads (4 waves, wr x wc = 2x2). Tile 64 rows x 256 cols, BK=32, 8 K-steps.
// T3/T4 pipeline: triple-buffered LDS, depth-2-ahead, raw s_barrier + counted
// s_waitcnt vmcnt(12) -- loads stay in flight across barriers, never drained to 0
// until the tail.
__global__ __launch_bounds__(256, 2) void k_fused(const float* __restrict__ x,
                                                  const unsigned short* __restrict__ Wt,
                                                  const float* __restrict__ wm,
                                                  const float* __restrict__ bfeat,
                                                  const int* __restrict__ bind,
                                                  float* __restrict__ dPart,
                                                  float* __restrict__ xgPart) {
    __shared__ float          xbuf[3][64 * 32];    // A: 3 x 8 KB
    __shared__ unsigned short bbuf[3][32 * 256];   // B: 3 x 16 KB
    __shared__ float wm_s[256];
    __shared__ float w_s[64];
    __shared__ float pxg[2][256];
    __shared__ float pden[2];
    __shared__ int   seg_s[64];
    __shared__ int   segid_s[4];
    __shared__ int   uni_s[4];

    const int t    = threadIdx.x;
    const int lane = t & 63;
    const int w    = t >> 6;
    const int wr   = w >> 1, wc = w & 1;
    const int fr   = lane & 15;
    const int fg   = lane >> 4;
    const size_t r0 = (size_t)blockIdx.x * 64;
    const int cp   = blockIdx.x & (NCOPY - 1);

    wm_s[t] = wm[t];
    pxg[0][t] = 0.f;
    pxg[1][t] = 0.f;
    if (t < 2) pden[t] = 0.f;
    if (t < 64) seg_s[t] = bind[r0 + t];

    // prologue: fill the 3-deep pipeline (18 loads/thread in flight)
    STAGE(0, 0);
    STAGE(1, 32);
    STAGE(2, 64);

    f32x4 acc[2][8];
#pragma unroll
    for (int m = 0; m < 2; m++)
#pragma unroll
        for (int n = 0; n < 8; n++) acc[m][n] = (f32x4){0.f, 0.f, 0.f, 0.f};
    float gp0 = 0.f, gp1 = 0.f;

#pragma unroll
    for (int s = 0; s < 8; s++) {
        const int buf = s % 3;
        // counted wait: oldest 6 (step s's) retired; steps s+1,s+2 stay in flight
        if (s <= 5)      asm volatile("s_waitcnt vmcnt(12)" ::: "memory");
        else if (s == 6) asm volatile("s_waitcnt vmcnt(6)"  ::: "memory");
        else             asm volatile("s_waitcnt vmcnt(0)"  ::: "memory");
        __builtin_amdgcn_sched_barrier(0);
        __builtin_amdgcn_s_barrier();      // all waves' step-s loads landed
        __builtin_amdgcn_sched_barrier(0);

        // ---- compute step s: pure LDS ----
        const float* xb = &xbuf[buf][0];
        const unsigned short* bb = &bbuf[buf][0];
        short8 b[8];
#pragma unroll
        for (int n = 0; n < 8; n++)
            b[n] = *reinterpret_cast<const short8*>(&bb[fg * 2048 + ((wc * 128 + n * 16 + fr) << 3)]);

        const float4 wa = *reinterpret_cast<const float4*>(&wm_s[s * 32 + fg * 8]);
        const float4 wbv = *reinterpret_cast<const float4*>(&wm_s[s * 32 + fg * 8 + 4]);
        {
            const int r  = wr * 32 + fr;
            const int sl = (fg * 2) ^ (r & 7);
            const float4 lo = *reinterpret_cast<const float4*>(&xb[r * 32 + sl * 4]);
            const float4 hi = *reinterpret_cast<const float4*>(&xb[r * 32 + (sl ^ 1) * 4]);
            gp0 += lo.x * wa.x + lo.y * wa.y + lo.z * wa.z + lo.w * wa.w
                 + hi.x * wbv.x + hi.y * wbv.y + hi.z * wbv.z + hi.w * wbv.w;
            const short8 a = pack8(lo, hi);
#pragma unroll
            for (int n = 0; n < 8; n++)
                acc[0][n] = __builtin_amdgcn_mfma_f32_16x16x32_bf16(a, b[n], acc[0][n], 0, 0, 0);
        }
        {
            const int r  = wr * 32 + 16 + fr;
            const int sl = (fg * 2) ^ (r & 7);
            const float4 lo = *reinterpret_cast<const float4*>(&xb[r * 32 + sl * 4]);
            const float4 hi = *reinterpret_cast<const float4*>(&xb[r * 32 + (sl ^ 1) * 4]);
            gp1 += lo.x * wa.x + lo.y * wa.y + lo.z * wa.z + lo.w * wa.w
                 + hi.x * wbv.x + hi.y * wbv.y + hi.z * wbv.z + hi.w * wbv.w;
            const short8 a = pack8(lo, hi);
#pragma unroll
            for (int n = 0; n < 8; n++)
                acc[1][n] = __builtin_amdgcn_mfma_f32_16x16x32_bf16(a, b[n], acc[1][n], 0, 0, 0);
        }

        // release buf[s%3]: all waves done reading, then refill it with step s+3
        asm volatile("s_waitcnt lgkmcnt(0)" ::: "memory");
        __builtin_amdgcn_sched_barrier(0);
        __builtin_amdgcn_s_barrier();
        __builtin_amdgcn_sched_barrier(0);
        if (s < 5) {
            const int kt = (s + 3) * 32;
            STAGE((s + 3) % 3, kt);
        }
    }

    // ---- gate -> e ----
    gp0 += __shfl_xor(gp0, 16, 64); gp0 += __shfl_xor(gp0, 32, 64);
    gp1 += __shfl_xor(gp1, 16, 64); gp1 += __shfl_xor(gp1, 32, 64);
    // exp(b_mask) cancels in the softmax -> dropped
    if (wc == 0 && lane < 16) {
        w_s[wr * 32 + lane]      = expf(gp0);
        w_s[wr * 32 + 16 + lane] = expf(gp1);
    }
    if (t < 4) {
        int s0 = seg_s[t * 16], ok = 1;
#pragma unroll
        for (int i = 1; i < 16; i++) ok &= (seg_s[t * 16 + i] == s0);
        segid_s[t] = s0;
        uni_s[t]   = ok;
    }
    __syncthreads();

    const int sid0 = seg_s[0];
    const int sid1 = seg_s[63];

    // ---- denom partials (LDS slots, global fallback for >2-segment blocks) ----
    if (t < 4) {
        if (uni_s[t]) {
            float s = 0.f;
#pragma unroll
            for (int i = 0; i < 16; i++) s += w_s[t * 16 + i];
            const int sid = segid_s[t];
            if (sid == sid0)      atomicAdd(&pden[0], s);
            else if (sid == sid1) atomicAdd(&pden[1], s);
            else atomicAdd(&dPart[cp * NB + sid], s);
        } else {
            for (int i = 0; i < 16; i++) {
                const int sd = seg_s[t * 16 + i];
                const float e = w_s[t * 16 + i];
                if (sd == sid0)      atomicAdd(&pden[0], e);
                else if (sd == sid1) atomicAdd(&pden[1], e);
                else atomicAdd(&dPart[cp * NB + sd], e);
            }
        }
    }

    // ---- epilogue: bias -> leaky -> *e -> segmented reduce -> LDS slots ----
#pragma unroll
    for (int m = 0; m < 2; m++) {
        const int g    = wr * 2 + m;
        const int uni  = uni_s[g];
        const int sid  = segid_s[g];
        const int rowb = wr * 32 + m * 16;
#pragma unroll
        for (int n = 0; n < 8; n++) {
            const int col = wc * 128 + n * 16 + fr;
            const float bia = bfeat[col];
            float vr[4];
#pragma unroll
            for (int r = 0; r < 4; r++) {
                const int row = rowb + fg * 4 + r;
                float v = acc[m][n][r] + bia;
                v = (v >= 0.f) ? v : SLOPE * v;
                vr[r] = v * w_s[row];
            }
            if (uni) {
                float s = vr[0] + vr[1] + vr[2] + vr[3];
                s += __shfl_xor(s, 16, 64);
                s += __shfl_xor(s, 32, 64);
                if (fg == 0) {
                    if (sid == sid0)      atomicAdd(&pxg[0][col], s);
                    else if (sid == sid1) atomicAdd(&pxg[1][col], s);
                    else atomicAdd(&xgPart[((size_t)(cp * NB + sid) << 8) + col], s);
                }
            } else {
#pragma unroll
                for (int r = 0; r < 4; r++) {
                    const int sd = seg_s[rowb + fg * 4 + r];
                    if (sd == sid0)      atomicAdd(&pxg[0][col], vr[r]);
                    else if (sd == sid1) atomicAdd(&pxg[1][col], vr[r]);
                    else atomicAdd(&xgPart[((size_t)(cp * NB + sd) << 8) + col], vr[r]);
                }
            }
        }
    }
    __syncthreads();

    // ---- flush block partials into XCD-striped copies ----
    atomicAdd(&xgPart[((size_t)(cp * NB + sid0) << 8) + t], pxg[0][t]);
    if (sid1 != sid0)
        atomicAdd(&xgPart[((size_t)(cp * NB + sid1) << 8) + t], pxg[1][t]);
    if (t == 0) atomicAdd(&dPart[cp * NB + sid0], pden[0]);
    if (t == 1 && sid1 != sid0) atomicAdd(&dPart[cp * NB + sid1], pden[1]);
}

// ---------- out = leaky_relu([xg/denom, xg_prev] @ W_t + b_t) + xg_prev ----------
__global__ __launch_bounds__(256) void k_out(const float* __restrict__ xgPart,
                                             const float* __restrict__ dPart,
                                             const float* __restrict__ xgp,
                                             const float* __restrict__ Wtr,
                                             const float* __restrict__ bt,
                                             float* __restrict__ out) {
    __shared__ float h[8][512];
    const int c  = threadIdx.x;
    const int b0 = blockIdx.x * 8;
#pragma unroll
    for (int r = 0; r < 8; r++) {
        const int b = b0 + r;
        float den = 0.f, s = 0.f;
#pragma unroll
        for (int cpy = 0; cpy < NCOPY; cpy++) {
            den += dPart[cpy * NB + b];
            s   += xgPart[((size_t)(cpy * NB + b) << 8) + c];
        }
        h[r][c]       = s / fmaxf(den, 1e-16f);
        h[r][EMB + c] = xgp[(size_t)b * EMB + c];
    }
    __syncthreads();
    float acc[8] = {0.f, 0.f, 0.f, 0.f, 0.f, 0.f, 0.f, 0.f};
    for (int k = 0; k < 2 * EMB; k++) {
        float wv = Wtr[(size_t)k * EMB + c];
#pragma unroll
        for (int r = 0; r < 8; r++) acc[r] += h[r][k] * wv;
    }
#pragma unroll
    for (int r = 0; r < 8; r++) {
        float v = acc[r] + bt[c];
        v = (v >= 0.f) ? v : SLOPE * v;
        out[(size_t)(b0 + r) * EMB + c] = v + xgp[(size_t)(b0 + r) * EMB + c];
    }
}

extern "C" void kernel_launch(void* const* d_in, const int* in_sizes, int n_in,
                              void* d_out, int out_size, void* d_ws, size_t ws_size,
                              hipStream_t stream) {
    const float* xgp  = (const float*)d_in[0];
    const float* x    = (const float*)d_in[1];
    const int*   bind = (const int*)d_in[2];
    const float* Wm   = (const float*)d_in[3];
    const float* Wf   = (const float*)d_in[5];
    const float* bf   = (const float*)d_in[6];
    const float* Wtr  = (const float*)d_in[7];
    const float* bt   = (const float*)d_in[8];
    float* out = (float*)d_out;

    char* ws = (char*)d_ws;
    unsigned short* Wt     = (unsigned short*)ws;                 // 128 KB
    float*          dPart  = (float*)(ws + 131072);               // 8*512 f32 = 16 KB
    float*          xgPart = (float*)(ws + 131072 + 16384);       // 8*512*256 f32 = 4 MB

    hipLaunchKernelGGL(k_init,  dim3(1028),       dim3(256), 0, stream,
                       (float4*)xgPart, (float4*)dPart);
    hipLaunchKernelGGL(k_prep,  dim3(256),        dim3(256), 0, stream, Wf, Wt);
    hipLaunchKernelGGL(k_fused, dim3(NROWS / 64), dim3(256), 0, stream,
                       x, Wt, Wm, bf, bind, dPart, xgPart);
    hipLaunchKernelGGL(k_out,   dim3(NB / 8),     dim3(256), 0, stream,
                       xgPart, dPart, xgp, Wtr, bt, out);
}

// Round 9
// 179.538 us; speedup vs baseline: 1.8986x; 1.1904x over previous
//
#include <hip/hip_runtime.h>
#include <cstdint>
#include <cstddef>

#define NROWS 262144
#define EMB 256
#define NB 512
#define NCOPY 8
#define SLOPE 0.01f

typedef __attribute__((ext_vector_type(8))) short short8;
typedef __attribute__((ext_vector_type(4))) float f32x4;

__device__ __forceinline__ unsigned short f2bf(float f) {
    unsigned u = __float_as_uint(f);
    u += 0x7FFFu + ((u >> 16) & 1u);
    return (unsigned short)(u >> 16);
}

__device__ __forceinline__ short8 pack8(const float4& lo, const float4& hi) {
    short8 s;
    s[0] = (short)f2bf(lo.x); s[1] = (short)f2bf(lo.y);
    s[2] = (short)f2bf(lo.z); s[3] = (short)f2bf(lo.w);
    s[4] = (short)f2bf(hi.x); s[5] = (short)f2bf(hi.y);
    s[6] = (short)f2bf(hi.z); s[7] = (short)f2bf(hi.w);
    return s;
}

// async 16B global -> LDS (DMA, no VGPR round trip)
__device__ __forceinline__ void gld16f(float* l, const float* g) {
    __builtin_amdgcn_global_load_lds(
        (const __attribute__((address_space(1))) unsigned int*)g,
        (__attribute__((address_space(3))) unsigned int*)l, 16, 0, 0);
}
__device__ __forceinline__ void gld16u(unsigned short* l, const unsigned short* g) {
    __builtin_amdgcn_global_load_lds(
        (const __attribute__((address_space(1))) unsigned int*)g,
        (__attribute__((address_space(3))) unsigned int*)l, 16, 0, 0);
}

// ---------- init: zero xgPart (8 copies) + dPart ----------
__global__ __launch_bounds__(256) void k_init(float4* xgPart4, float4* dPart4) {
    int i = blockIdx.x * 256 + threadIdx.x;
    if (i < NCOPY * NB * EMB / 4) xgPart4[i] = (float4){0.f, 0.f, 0.f, 0.f};
    else dPart4[i - NCOPY * NB * EMB / 4] = (float4){0.f, 0.f, 0.f, 0.f};
}

// ---------- prep: W_feat -> bf16 chunked layout Wt2[k>>3][col][k&7] ----------
// Staging a K-step then reads 4 CONTIGUOUS 4KB slabs (lane-contiguous, 8 lanes/line)
// instead of 512B-stride 16B-granule scatters (1 line/lane).
__global__ __launch_bounds__(256) void k_prep(const float* __restrict__ Wf,
                                              unsigned short* __restrict__ Wt2) {
    int b = blockIdx.x, t = threadIdx.x;            // b = k index, t = col
    float v = Wf[(size_t)b * EMB + t];              // W_feat[k=b][col=t]
    Wt2[((size_t)(b >> 3) << 11) + (t << 3) + (b & 7)] = f2bf(v);
}

// stage K-step (32 k) into buffer B: A 64x32 f32 (row-chunk XOR swizzled src),
// B = 4 contiguous 4KB slabs of Wt2. 6 DMA instructions per thread.
#define STAGE(B, KT) do {                                                         \
    _Pragma("unroll")                                                             \
    for (int q = 0; q < 2; q++) {                                                 \
        const int i_ = q * 256 + t;                                               \
        const int row_ = i_ >> 3, c_ = i_ & 7;                                    \
        const int cs_ = c_ ^ (row_ & 7);                                          \
        gld16f(&xbuf[B][i_ * 4], x + ((r0 + row_) << 8) + (KT) + (cs_ << 2));     \
    }                                                                             \
    _Pragma("unroll")                                                             \
    for (int q = 0; q < 4; q++) {                                                 \
        gld16u(&bbuf[B][q * 2048 + t * 8],                                        \
               Wt2 + (((size_t)((KT) >> 3) + q) << 11) + t * 8);                  \
    }                                                                             \
} while (0)

// ---------- fused: gate + exp + bf16 MFMA feat GEMM + weighted segment reduce ----------
// 256 threads (4 waves, wr x wc = 2x2). Tile 64 rows x 256 cols, BK=32, 8 K-steps.
// Triple-buffered LDS, depth-2-ahead, counted vmcnt. B staging lane-contiguous (R9).
__global__ __launch_bounds__(256, 2) void k_fused(const float* __restrict__ x,
                                                  const unsigned short* __restrict__ Wt2,
                                                  const float* __restrict__ wm,
                                                  const float* __restrict__ bfeat,
                                                  const int* __restrict__ bind,
                                                  float* __restrict__ dPart,
                                                  float* __restrict__ xgPart) {
    __shared__ float          xbuf[3][64 * 32];    // A: 3 x 8 KB
    __shared__ unsigned short bbuf[3][32 * 256];   // B: 3 x 16 KB, [k-chunk q][col][8]
    __shared__ float wm_s[256];
    __shared__ float w_s[64];
    __shared__ float pxg[2][256];
    __shared__ float pden[2];
    __shared__ int   seg_s[64];
    __shared__ int   segid_s[4];
    __shared__ int   uni_s[4];

    const int t    = threadIdx.x;
    const int lane = t & 63;
    const int w    = t >> 6;
    const int wr   = w >> 1, wc = w & 1;
    const int fr   = lane & 15;
    const int fg   = lane >> 4;
    const size_t r0 = (size_t)blockIdx.x * 64;
    const int cp   = blockIdx.x & (NCOPY - 1);

    wm_s[t] = wm[t];
    pxg[0][t] = 0.f;
    pxg[1][t] = 0.f;
    if (t < 2) pden[t] = 0.f;
    if (t < 64) seg_s[t] = bind[r0 + t];

    // prologue: fill the 3-deep pipeline (18 loads/thread in flight)
    STAGE(0, 0);
    STAGE(1, 32);
    STAGE(2, 64);

    f32x4 acc[2][8];
#pragma unroll
    for (int m = 0; m < 2; m++)
#pragma unroll
        for (int n = 0; n < 8; n++) acc[m][n] = (f32x4){0.f, 0.f, 0.f, 0.f};
    float gp0 = 0.f, gp1 = 0.f;

#pragma unroll
    for (int s = 0; s < 8; s++) {
        const int buf = s % 3;
        // counted wait: oldest 6 (step s's) retired; steps s+1,s+2 stay in flight
        if (s <= 5)      asm volatile("s_waitcnt vmcnt(12)" ::: "memory");
        else if (s == 6) asm volatile("s_waitcnt vmcnt(6)"  ::: "memory");
        else             asm volatile("s_waitcnt vmcnt(0)"  ::: "memory");
        __builtin_amdgcn_sched_barrier(0);
        __builtin_amdgcn_s_barrier();      // all waves' step-s loads landed
        __builtin_amdgcn_sched_barrier(0);

        // ---- compute step s: pure LDS ----
        const float* xb = &xbuf[buf][0];
        const unsigned short* bb = &bbuf[buf][0];
        short8 b[8];
#pragma unroll
        for (int n = 0; n < 8; n++)
            b[n] = *reinterpret_cast<const short8*>(&bb[fg * 2048 + ((wc * 128 + n * 16 + fr) << 3)]);

        const float4 wa = *reinterpret_cast<const float4*>(&wm_s[s * 32 + fg * 8]);
        const float4 wbv = *reinterpret_cast<const float4*>(&wm_s[s * 32 + fg * 8 + 4]);
        {
            const int r  = wr * 32 + fr;
            const int sl = (fg * 2) ^ (r & 7);
            const float4 lo = *reinterpret_cast<const float4*>(&xb[r * 32 + sl * 4]);
            const float4 hi = *reinterpret_cast<const float4*>(&xb[r * 32 + (sl ^ 1) * 4]);
            gp0 += lo.x * wa.x + lo.y * wa.y + lo.z * wa.z + lo.w * wa.w
                 + hi.x * wbv.x + hi.y * wbv.y + hi.z * wbv.z + hi.w * wbv.w;
            const short8 a = pack8(lo, hi);
#pragma unroll
            for (int n = 0; n < 8; n++)
                acc[0][n] = __builtin_amdgcn_mfma_f32_16x16x32_bf16(a, b[n], acc[0][n], 0, 0, 0);
        }
        {
            const int r  = wr * 32 + 16 + fr;
            const int sl = (fg * 2) ^ (r & 7);
            const float4 lo = *reinterpret_cast<const float4*>(&xb[r * 32 + sl * 4]);
            const float4 hi = *reinterpret_cast<const float4*>(&xb[r * 32 + (sl ^ 1) * 4]);
            gp1 += lo.x * wa.x + lo.y * wa.y + lo.z * wa.z + lo.w * wa.w
                 + hi.x * wbv.x + hi.y * wbv.y + hi.z * wbv.z + hi.w * wbv.w;
            const short8 a = pack8(lo, hi);
#pragma unroll
            for (int n = 0; n < 8; n++)
                acc[1][n] = __builtin_amdgcn_mfma_f32_16x16x32_bf16(a, b[n], acc[1][n], 0, 0, 0);
        }

        // release buf[s%3]: all waves done reading, then refill it with step s+3
        asm volatile("s_waitcnt lgkmcnt(0)" ::: "memory");
        __builtin_amdgcn_sched_barrier(0);
        __builtin_amdgcn_s_barrier();
        __builtin_amdgcn_sched_barrier(0);
        if (s < 5) {
            const int kt = (s + 3) * 32;
            STAGE((s + 3) % 3, kt);
        }
    }

    // ---- gate -> e ----
    gp0 += __shfl_xor(gp0, 16, 64); gp0 += __shfl_xor(gp0, 32, 64);
    gp1 += __shfl_xor(gp1, 16, 64); gp1 += __shfl_xor(gp1, 32, 64);
    // exp(b_mask) cancels in the softmax -> dropped
    if (wc == 0 && lane < 16) {
        w_s[wr * 32 + lane]      = expf(gp0);
        w_s[wr * 32 + 16 + lane] = expf(gp1);
    }
    if (t < 4) {
        int s0 = seg_s[t * 16], ok = 1;
#pragma unroll
        for (int i = 1; i < 16; i++) ok &= (seg_s[t * 16 + i] == s0);
        segid_s[t] = s0;
        uni_s[t]   = ok;
    }
    __syncthreads();

    const int sid0 = seg_s[0];
    const int sid1 = seg_s[63];

    // ---- denom partials (LDS slots, global fallback for >2-segment blocks) ----
    if (t < 4) {
        if (uni_s[t]) {
            float s = 0.f;
#pragma unroll
            for (int i = 0; i < 16; i++) s += w_s[t * 16 + i];
            const int sid = segid_s[t];
            if (sid == sid0)      atomicAdd(&pden[0], s);
            else if (sid == sid1) atomicAdd(&pden[1], s);
            else atomicAdd(&dPart[cp * NB + sid], s);
        } else {
            for (int i = 0; i < 16; i++) {
                const int sd = seg_s[t * 16 + i];
                const float e = w_s[t * 16 + i];
                if (sd == sid0)      atomicAdd(&pden[0], e);
                else if (sd == sid1) atomicAdd(&pden[1], e);
                else atomicAdd(&dPart[cp * NB + sd], e);
            }
        }
    }

    // ---- epilogue: bias -> leaky -> *e -> segmented reduce -> LDS slots ----
#pragma unroll
    for (int m = 0; m < 2; m++) {
        const int g    = wr * 2 + m;
        const int uni  = uni_s[g];
        const int sid  = segid_s[g];
        const int rowb = wr * 32 + m * 16;
#pragma unroll
        for (int n = 0; n < 8; n++) {
            const int col = wc * 128 + n * 16 + fr;
            const float bia = bfeat[col];
            float vr[4];
#pragma unroll
            for (int r = 0; r < 4; r++) {
                const int row = rowb + fg * 4 + r;
                float v = acc[m][n][r] + bia;
                v = (v >= 0.f) ? v : SLOPE * v;
                vr[r] = v * w_s[row];
            }
            if (uni) {
                float s = vr[0] + vr[1] + vr[2] + vr[3];
                s += __shfl_xor(s, 16, 64);
                s += __shfl_xor(s, 32, 64);
                if (fg == 0) {
                    if (sid == sid0)      atomicAdd(&pxg[0][col], s);
                    else if (sid == sid1) atomicAdd(&pxg[1][col], s);
                    else atomicAdd(&xgPart[((size_t)(cp * NB + sid) << 8) + col], s);
                }
            } else {
#pragma unroll
                for (int r = 0; r < 4; r++) {
                    const int sd = seg_s[rowb + fg * 4 + r];
                    if (sd == sid0)      atomicAdd(&pxg[0][col], vr[r]);
                    else if (sd == sid1) atomicAdd(&pxg[1][col], vr[r]);
                    else atomicAdd(&xgPart[((size_t)(cp * NB + sd) << 8) + col], vr[r]);
                }
            }
        }
    }
    __syncthreads();

    // ---- flush block partials into XCD-striped copies ----
    atomicAdd(&xgPart[((size_t)(cp * NB + sid0) << 8) + t], pxg[0][t]);
    if (sid1 != sid0)
        atomicAdd(&xgPart[((size_t)(cp * NB + sid1) << 8) + t], pxg[1][t]);
    if (t == 0) atomicAdd(&dPart[cp * NB + sid0], pden[0]);
    if (t == 1 && sid1 != sid0) atomicAdd(&dPart[cp * NB + sid1], pden[1]);
}

// ---------- out = leaky_relu([xg/denom, xg_prev] @ W_t + b_t) + xg_prev ----------
__global__ __launch_bounds__(256) void k_out(const float* __restrict__ xgPart,
                                             const float* __restrict__ dPart,
                                             const float* __restrict__ xgp,
                                             const float* __restrict__ Wtr,
                                             const float* __restrict__ bt,
                                             float* __restrict__ out) {
    __shared__ float h[8][512];
    const int c  = threadIdx.x;
    const int b0 = blockIdx.x * 8;
#pragma unroll
    for (int r = 0; r < 8; r++) {
        const int b = b0 + r;
        float den = 0.f, s = 0.f;
#pragma unroll
        for (int cpy = 0; cpy < NCOPY; cpy++) {
            den += dPart[cpy * NB + b];
            s   += xgPart[((size_t)(cpy * NB + b) << 8) + c];
        }
        h[r][c]       = s / fmaxf(den, 1e-16f);
        h[r][EMB + c] = xgp[(size_t)b * EMB + c];
    }
    __syncthreads();
    float acc[8] = {0.f, 0.f, 0.f, 0.f, 0.f, 0.f, 0.f, 0.f};
    for (int k = 0; k < 2 * EMB; k++) {
        float wv = Wtr[(size_t)k * EMB + c];
#pragma unroll
        for (int r = 0; r < 8; r++) acc[r] += h[r][k] * wv;
    }
#pragma unroll
    for (int r = 0; r < 8; r++) {
        float v = acc[r] + bt[c];
        v = (v >= 0.f) ? v : SLOPE * v;
        out[(size_t)(b0 + r) * EMB + c] = v + xgp[(size_t)(b0 + r) * EMB + c];
    }
}

extern "C" void kernel_launch(void* const* d_in, const int* in_sizes, int n_in,
                              void* d_out, int out_size, void* d_ws, size_t ws_size,
                              hipStream_t stream) {
    const float* xgp  = (const float*)d_in[0];
    const float* x    = (const float*)d_in[1];
    const int*   bind = (const int*)d_in[2];
    const float* Wm   = (const float*)d_in[3];
    const float* Wf   = (const float*)d_in[5];
    const float* bf   = (const float*)d_in[6];
    const float* Wtr  = (const float*)d_in[7];
    const float* bt   = (const float*)d_in[8];
    float* out = (float*)d_out;

    char* ws = (char*)d_ws;
    unsigned short* Wt2    = (unsigned short*)ws;                 // 128 KB (chunked)
    float*          dPart  = (float*)(ws + 131072);               // 8*512 f32 = 16 KB
    float*          xgPart = (float*)(ws + 131072 + 16384);       // 8*512*256 f32 = 4 MB

    hipLaunchKernelGGL(k_init,  dim3(1028),       dim3(256), 0, stream,
                       (float4*)xgPart, (float4*)dPart);
    hipLaunchKernelGGL(k_prep,  dim3(256),        dim3(256), 0, stream, Wf, Wt2);
    hipLaunchKernelGGL(k_fused, dim3(NROWS / 64), dim3(256), 0, stream,
                       x, Wt2, Wm, bf, bind, dPart, xgPart);
    hipLaunchKernelGGL(k_out,   dim3(NB / 8),     dim3(256), 0, stream,
                       xgPart, dPart, xgp, Wtr, bt, out);
}